// Round 3
// baseline (210.876 us; speedup 1.0000x reference)
//
#include <hip/hip_runtime.h>
#include <math.h>

#define HH 256
#define WW 256
#define BB 32
#define NW 8  // 256 rows = 8 x u32 words per column bitmask

// ---------------------------------------------------------------------------
// Kernel A: build column bitmasks.  P bit = (pred > 0.5), T bit = (target==1).
// Grid: BB*NW*4 = 1024 blocks; block = (b, word-row j, column-quarter wq).
// Each of the 4 waves builds 8 rows x 64 cols; bytes merged via LDS.
// Block 0 thread 0 also zeroes the reduction accumulator/ticket for kernel B.
// ---------------------------------------------------------------------------
__global__ __launch_bounds__(256) void bitmask_kernel(
    const float* __restrict__ pred, const float* __restrict__ tgt,
    unsigned int* __restrict__ P, unsigned int* __restrict__ T,
    double* __restrict__ acc, unsigned int* __restrict__ cnt) {
  if (blockIdx.x == 0 && threadIdx.x == 0) { *acc = 0.0; *cnt = 0u; }

  const int b  = blockIdx.x >> 5;
  const int j  = (blockIdx.x >> 2) & 7;
  const int wq = blockIdx.x & 3;
  const int r    = threadIdx.x >> 6;   // wave id: row-subset (8 rows)
  const int lane = threadIdx.x & 63;   // column within quarter
  const int col  = wq * 64 + lane;
  const int row0 = j * 32 + r * 8;

  const float* pin = pred + (size_t)b * (HH * WW) + row0 * WW + col;
  const float* tin = tgt  + (size_t)b * (HH * WW) + row0 * WW + col;
  unsigned int pb = 0, tb = 0;
#pragma unroll
  for (int i = 0; i < 8; ++i) {
    pb |= (pin[i * WW] > 0.5f ? 1u : 0u) << i;
    tb |= (tin[i * WW] == 1.0f ? 1u : 0u) << i;
  }

  __shared__ unsigned int sP[4][64], sT[4][64];
  sP[r][lane] = pb << (r * 8);
  sT[r][lane] = tb << (r * 8);
  __syncthreads();
  if (r == 0) {
    unsigned int fullP = sP[0][lane] | sP[1][lane] | sP[2][lane] | sP[3][lane];
    unsigned int fullT = sT[0][lane] | sT[1][lane] | sT[2][lane] | sT[3][lane];
    P[((size_t)b * NW + j) * WW + col] = fullP;
    T[((size_t)b * NW + j) * WW + col] = fullT;
  }
}

// ---------------------------------------------------------------------------
// Kernel B: per-row fused pipeline + global reduction.
// Thread y (column): loads its column's P/T bitmask words; for each of
// pred/target, XOR-folds by its own bit so a single scan finds the nearest
// DIFFERING pixel (the own-valued map has distance 0 exactly). Then the
// exact early-exit min-plus over the row in LDS, fused loss, block reduce,
// and a double atomicAdd + ticket so the last block writes the mean.
// ---------------------------------------------------------------------------
__global__ __launch_bounds__(256) void minplus_kernel(
    const unsigned int* __restrict__ P, const unsigned int* __restrict__ T,
    double* __restrict__ acc, unsigned int* __restrict__ cnt,
    float* __restrict__ out) {
  const int row = blockIdx.x;     // b*HH + h
  const int b = row >> 8;
  const int h = row & 255;
  const int y = threadIdx.x;

  // block-uniform position masks (scalarized by the compiler)
  const int wj = h >> 5, bi = h & 31;
  unsigned int mLE[NW], mGE[NW];
#pragma unroll
  for (int j = 0; j < NW; ++j) {
    mLE[j] = (j < wj) ? 0xFFFFFFFFu : ((j == wj) ? ((2u << bi) - 1u) : 0u);
    mGE[j] = (j > wj) ? 0xFFFFFFFFu : ((j == wj) ? ~((1u << bi) - 1u) : 0u);
  }

  unsigned int Pw[NW], Tw[NW];
#pragma unroll
  for (int j = 0; j < NW; ++j) {
    Pw[j] = P[((size_t)b * NW + j) * WW + y];
    Tw[j] = T[((size_t)b * NW + j) * WW + y];
  }

  // own bits at row h (uniform word index -> unrolled uniform select)
  unsigned int selP = 0, selT = 0;
#pragma unroll
  for (int j = 0; j < NW; ++j) {
    if (wj == j) { selP = Pw[j]; selT = Tw[j]; }
  }
  const unsigned int ownP = (selP >> bi) & 1u;
  const unsigned int ownT = (selT >> bi) & 1u;
  const unsigned int sgnP = 0u - ownP;   // 0 or ~0
  const unsigned int sgnT = 0u - ownT;

  // nearest differing bit: above (hi) and below (lo)
  int hiP = -2000, hiT = -2000, loP = 2000, loT = 2000;
#pragma unroll
  for (int j = 0; j < NW; ++j) {          // ascending: last nonzero wins
    unsigned int aP = (Pw[j] ^ sgnP) & mLE[j];
    unsigned int aT = (Tw[j] ^ sgnT) & mLE[j];
    if (aP) hiP = 32 * j + 31 - __builtin_clz(aP);
    if (aT) hiT = 32 * j + 31 - __builtin_clz(aT);
  }
#pragma unroll
  for (int j = NW - 1; j >= 0; --j) {     // descending: first nonzero wins
    unsigned int aP = (Pw[j] ^ sgnP) & mGE[j];
    unsigned int aT = (Tw[j] ^ sgnT) & mGE[j];
    if (aP) loP = 32 * j + __builtin_ctz(aP);
    if (aT) loT = 32 * j + __builtin_ctz(aT);
  }
  const int dP = min(min(h - hiP, loP - h), 512);  // cap = H+W
  const int dT = min(min(h - hiT, loT - h), 512);
  const float dp2 = (float)(dP * dP);
  const float dt2 = (float)(dT * dT);

  __shared__ float4 s[WW];
  s[y] = make_float4(ownP ? 0.f : dp2, ownP ? dp2 : 0.f,
                     ownT ? 0.f : dt2, ownT ? dt2 : 0.f);
  __syncthreads();

  float4 me = s[y];
  float m0 = me.x, m1 = me.y, m2 = me.z, m3 = me.w;

  for (int k = 1; k < WW; ++k) {
    float c = (float)(k * k);
    float mx = fmaxf(fmaxf(m0, m1), fmaxf(m2, m3));
    if (c >= mx) break;                   // exact: remaining candidates >= k^2
    int lo = y - k;
    if (lo >= 0) {
      float4 v = s[lo];
      m0 = fminf(m0, v.x + c); m1 = fminf(m1, v.y + c);
      m2 = fminf(m2, v.z + c); m3 = fminf(m3, v.w + c);
    }
    int hic = y + k;
    if (hic < WW) {
      float4 v = s[hic];
      m0 = fminf(m0, v.x + c); m1 = fminf(m1, v.y + c);
      m2 = fminf(m2, v.z + c); m3 = fminf(m3, v.w + c);
    }
  }

  float pd = sqrtf(m0) + sqrtf(m1);       // pred_dist
  float td = sqrtf(m2) + sqrtf(m3);       // target_dist
  float diff = pd - td;
  float val = diff * diff * td * td;      // (pd-td)^2 * td^ALPHA, ALPHA=2

  for (int off = 32; off > 0; off >>= 1) val += __shfl_down(val, off);
  __shared__ float wsum[4];
  if ((threadIdx.x & 63) == 0) wsum[threadIdx.x >> 6] = val;
  __syncthreads();

  if (threadIdx.x == 0) {
    float blocksum = (wsum[0] + wsum[1]) + (wsum[2] + wsum[3]);
    atomicAdd(acc, (double)blocksum);
    __threadfence();
    unsigned int t = atomicAdd(cnt, 1u);
    if (t == (unsigned int)(BB * HH - 1)) {
      double total = atomicAdd(acc, 0.0);  // atomic read: all adds visible
      out[0] = (float)(total / (double)((size_t)BB * HH * WW));
    }
  }
}

extern "C" void kernel_launch(void* const* d_in, const int* in_sizes, int n_in,
                              void* d_out, int out_size, void* d_ws, size_t ws_size,
                              hipStream_t stream) {
  const float* pred = (const float*)d_in[0];
  const float* tgt  = (const float*)d_in[1];
  float* out = (float*)d_out;

  // ws layout: P bitmasks (256 KB), T bitmasks (256 KB), acc (8B), cnt (4B)
  unsigned int* P = (unsigned int*)d_ws;
  unsigned int* T = P + (size_t)BB * NW * WW;
  double* acc = (double*)(T + (size_t)BB * NW * WW);
  unsigned int* cnt = (unsigned int*)(acc + 1);

  hipLaunchKernelGGL(bitmask_kernel, dim3(BB * NW * 4), dim3(256), 0, stream,
                     pred, tgt, P, T, acc, cnt);
  hipLaunchKernelGGL(minplus_kernel, dim3(BB * HH), dim3(256), 0, stream,
                     P, T, acc, cnt, out);
}

// Round 4
// 37.338 us; speedup vs baseline: 5.6478x; 5.6478x over previous
//
#include <hip/hip_runtime.h>
#include <math.h>

#define HH 256
#define WW 256
#define BB 32
#define NW 8  // 256 rows = 8 x u32 words per column bitmask

// ---------------------------------------------------------------------------
// Kernel A: build column bitmasks.  P bit = (pred > 0.5), T bit = (target==1).
// Grid: BB*NW*4 = 1024 blocks; block = (b, word-row j, column-quarter wq).
// Each of the 4 waves builds 8 rows x 64 cols; bytes merged via LDS.
// ---------------------------------------------------------------------------
__global__ __launch_bounds__(256) void bitmask_kernel(
    const float* __restrict__ pred, const float* __restrict__ tgt,
    unsigned int* __restrict__ P, unsigned int* __restrict__ T) {
  const int b  = blockIdx.x >> 5;
  const int j  = (blockIdx.x >> 2) & 7;
  const int wq = blockIdx.x & 3;
  const int r    = threadIdx.x >> 6;   // wave id: row-subset (8 rows)
  const int lane = threadIdx.x & 63;   // column within quarter
  const int col  = wq * 64 + lane;
  const int row0 = j * 32 + r * 8;

  const float* pin = pred + (size_t)b * (HH * WW) + row0 * WW + col;
  const float* tin = tgt  + (size_t)b * (HH * WW) + row0 * WW + col;
  unsigned int pb = 0, tb = 0;
#pragma unroll
  for (int i = 0; i < 8; ++i) {
    pb |= (pin[i * WW] > 0.5f ? 1u : 0u) << i;
    tb |= (tin[i * WW] == 1.0f ? 1u : 0u) << i;
  }

  __shared__ unsigned int sP[4][64], sT[4][64];
  sP[r][lane] = pb << (r * 8);
  sT[r][lane] = tb << (r * 8);
  __syncthreads();
  if (r == 0) {
    unsigned int fullP = sP[0][lane] | sP[1][lane] | sP[2][lane] | sP[3][lane];
    unsigned int fullT = sT[0][lane] | sT[1][lane] | sT[2][lane] | sT[3][lane];
    P[((size_t)b * NW + j) * WW + col] = fullP;
    T[((size_t)b * NW + j) * WW + col] = fullT;
  }
}

// ---------------------------------------------------------------------------
// Kernel B: per-row fused pipeline.  Thread y (column): loads its column's
// P/T bitmask words; XOR-folds by its own bit so a single scan finds the
// nearest DIFFERING pixel (own-valued map has distance 0 exactly). Then the
// exact early-exit min-plus over the row in LDS, fused loss, block reduce,
// plain partial[row] store (no atomics — f64 atomicAdd CAS-loop serialized
// at ~200us in round 3).
// ---------------------------------------------------------------------------
__global__ __launch_bounds__(256) void minplus_kernel(
    const unsigned int* __restrict__ P, const unsigned int* __restrict__ T,
    float* __restrict__ partial) {
  const int row = blockIdx.x;     // b*HH + h
  const int b = row >> 8;
  const int h = row & 255;
  const int y = threadIdx.x;

  // block-uniform position masks (scalarized by the compiler)
  const int wj = h >> 5, bi = h & 31;
  unsigned int mLE[NW], mGE[NW];
#pragma unroll
  for (int j = 0; j < NW; ++j) {
    mLE[j] = (j < wj) ? 0xFFFFFFFFu : ((j == wj) ? ((2u << bi) - 1u) : 0u);
    mGE[j] = (j > wj) ? 0xFFFFFFFFu : ((j == wj) ? ~((1u << bi) - 1u) : 0u);
  }

  unsigned int Pw[NW], Tw[NW];
#pragma unroll
  for (int j = 0; j < NW; ++j) {
    Pw[j] = P[((size_t)b * NW + j) * WW + y];
    Tw[j] = T[((size_t)b * NW + j) * WW + y];
  }

  // own bits at row h (uniform word index -> unrolled uniform select)
  unsigned int selP = 0, selT = 0;
#pragma unroll
  for (int j = 0; j < NW; ++j) {
    if (wj == j) { selP = Pw[j]; selT = Tw[j]; }
  }
  const unsigned int ownP = (selP >> bi) & 1u;
  const unsigned int ownT = (selT >> bi) & 1u;
  const unsigned int sgnP = 0u - ownP;   // 0 or ~0
  const unsigned int sgnT = 0u - ownT;

  // nearest differing bit: above (hi) and below (lo)
  int hiP = -2000, hiT = -2000, loP = 2000, loT = 2000;
#pragma unroll
  for (int j = 0; j < NW; ++j) {          // ascending: last nonzero wins
    unsigned int aP = (Pw[j] ^ sgnP) & mLE[j];
    unsigned int aT = (Tw[j] ^ sgnT) & mLE[j];
    if (aP) hiP = 32 * j + 31 - __builtin_clz(aP);
    if (aT) hiT = 32 * j + 31 - __builtin_clz(aT);
  }
#pragma unroll
  for (int j = NW - 1; j >= 0; --j) {     // descending: first nonzero wins
    unsigned int aP = (Pw[j] ^ sgnP) & mGE[j];
    unsigned int aT = (Tw[j] ^ sgnT) & mGE[j];
    if (aP) loP = 32 * j + __builtin_ctz(aP);
    if (aT) loT = 32 * j + __builtin_ctz(aT);
  }
  const int dP = min(min(h - hiP, loP - h), 512);  // cap = H+W
  const int dT = min(min(h - hiT, loT - h), 512);
  const float dp2 = (float)(dP * dP);
  const float dt2 = (float)(dT * dT);

  __shared__ float4 s[WW];
  s[y] = make_float4(ownP ? 0.f : dp2, ownP ? dp2 : 0.f,
                     ownT ? 0.f : dt2, ownT ? dt2 : 0.f);
  __syncthreads();

  float4 me = s[y];
  float m0 = me.x, m1 = me.y, m2 = me.z, m3 = me.w;

  for (int k = 1; k < WW; ++k) {
    float c = (float)(k * k);
    float mx = fmaxf(fmaxf(m0, m1), fmaxf(m2, m3));
    if (c >= mx) break;                   // exact: remaining candidates >= k^2
    int lo = y - k;
    if (lo >= 0) {
      float4 v = s[lo];
      m0 = fminf(m0, v.x + c); m1 = fminf(m1, v.y + c);
      m2 = fminf(m2, v.z + c); m3 = fminf(m3, v.w + c);
    }
    int hic = y + k;
    if (hic < WW) {
      float4 v = s[hic];
      m0 = fminf(m0, v.x + c); m1 = fminf(m1, v.y + c);
      m2 = fminf(m2, v.z + c); m3 = fminf(m3, v.w + c);
    }
  }

  float pd = sqrtf(m0) + sqrtf(m1);       // pred_dist
  float td = sqrtf(m2) + sqrtf(m3);       // target_dist
  float diff = pd - td;
  float val = diff * diff * td * td;      // (pd-td)^2 * td^ALPHA, ALPHA=2

  for (int off = 32; off > 0; off >>= 1) val += __shfl_down(val, off);
  __shared__ float wsum[4];
  if ((threadIdx.x & 63) == 0) wsum[threadIdx.x >> 6] = val;
  __syncthreads();
  if (threadIdx.x == 0)
    partial[row] = (wsum[0] + wsum[1]) + (wsum[2] + wsum[3]);
}

// ---------------------------------------------------------------------------
// Kernel C: reduce 8192 row partials in double, write mean.
// ---------------------------------------------------------------------------
__global__ __launch_bounds__(256) void finalize_kernel(
    const float* __restrict__ partial, float* __restrict__ out) {
  __shared__ double sd[256];
  double sum = 0.0;
  for (int i = threadIdx.x; i < BB * HH; i += 256) sum += (double)partial[i];
  sd[threadIdx.x] = sum;
  __syncthreads();
  for (int stride = 128; stride > 0; stride >>= 1) {
    if (threadIdx.x < stride) sd[threadIdx.x] += sd[threadIdx.x + stride];
    __syncthreads();
  }
  if (threadIdx.x == 0)
    out[0] = (float)(sd[0] / (double)((size_t)BB * HH * WW));
}

extern "C" void kernel_launch(void* const* d_in, const int* in_sizes, int n_in,
                              void* d_out, int out_size, void* d_ws, size_t ws_size,
                              hipStream_t stream) {
  const float* pred = (const float*)d_in[0];
  const float* tgt  = (const float*)d_in[1];
  float* out = (float*)d_out;

  // ws layout: P bitmasks (256 KB), T bitmasks (256 KB), partial (32 KB)
  unsigned int* P = (unsigned int*)d_ws;
  unsigned int* T = P + (size_t)BB * NW * WW;
  float* partial = (float*)(T + (size_t)BB * NW * WW);

  hipLaunchKernelGGL(bitmask_kernel, dim3(BB * NW * 4), dim3(256), 0, stream,
                     pred, tgt, P, T);
  hipLaunchKernelGGL(minplus_kernel, dim3(BB * HH), dim3(256), 0, stream,
                     P, T, partial);
  hipLaunchKernelGGL(finalize_kernel, dim3(1), dim3(256), 0, stream,
                     partial, out);
}